// Round 5
// baseline (445.936 us; speedup 1.0000x reference)
//
#include <hip/hip_runtime.h>
#include <hip/hip_fp16.h>
#include <math.h>

// ---------------------------------------------------------------------------
// SolventGCN round 5: degree-sorted aggregation + fp16 activations end-to-end.
//   zero -> p1_partition -> p2_scanbuckets -> p3_build(+degree-sort perm)
//   -> gemmBoth0 -> 3x { aggBoth (perm order, fp16 out) / gemmBoth (fp16 in) }
//   -> poolDense (fused pooling + MLP).  11 launches.
// Node space: c ids [0,Nc) in buckets 0..Nc_pad/512, s ids [Nc_pad, Nc_pad+Ns)
// (bucket-padded so no bucket mixes sides). Packed edge = (local_dst<<17)|src.
// ---------------------------------------------------------------------------

static inline int cdiv(int a, int b) { return (a + b - 1) / b; }

#define BUCKET_CAP 8192
#define P1_CHUNK   4096

__global__ void zero_int(int* __restrict__ p, int n) {
    int i = blockIdx.x * blockDim.x + threadIdx.x;
    if (i < n) p[i] = 0;
}

// ---- pass 1: partition edges into buckets (packed) ----
__global__ __launch_bounds__(256) void p1_partition(const int* __restrict__ c_edge, int Ec,
                                                    const int* __restrict__ s_edge, int Es,
                                                    int Nc_pad, int Etot, int nbuck,
                                                    int* __restrict__ bucket_fill,
                                                    unsigned* __restrict__ pk) {
    __shared__ unsigned       wbuf[P1_CHUNK];
    __shared__ unsigned short bbuf[P1_CHUNK];
    __shared__ int            hist[512];
    int e0 = blockIdx.x * P1_CHUNK;
    int n  = Etot - e0;
    if (n > P1_CHUNK) n = P1_CHUNK;
    for (int i = threadIdx.x; i < nbuck; i += 256) hist[i] = 0;
    __syncthreads();
    for (int i = threadIdx.x; i < n; i += 256) {
        int e = e0 + i, src, g;
        if (e < Ec) { src = c_edge[e]; g = c_edge[Ec + e]; }
        else        { int e2 = e - Ec; src = s_edge[e2]; g = Nc_pad + s_edge[Es + e2]; }
        int b   = g >> 9;
        wbuf[i] = ((unsigned)(g & 511) << 17) | (unsigned)src;
        bbuf[i] = (unsigned short)b;
        atomicAdd(&hist[b], 1);
    }
    __syncthreads();
    for (int i = threadIdx.x; i < nbuck; i += 256) {
        int h = hist[i];
        hist[i] = h ? atomicAdd(&bucket_fill[i], h) : 0;
    }
    __syncthreads();
    for (int i = threadIdx.x; i < n; i += 256) {
        int b    = bbuf[i];
        int slot = atomicAdd(&hist[b], 1);
        if (slot < BUCKET_CAP) pk[(size_t)b * BUCKET_CAP + slot] = wbuf[i];
    }
}

// ---- pass 2: exclusive scan of bucket fills ----
__global__ __launch_bounds__(512) void p2_scanbuckets(const int* __restrict__ fill, int nbuck,
                                                      int* __restrict__ basearr,
                                                      int* __restrict__ off_all, int Ntot_pad, int Etot) {
    __shared__ int sh[512];
    int v = (threadIdx.x < nbuck) ? fill[threadIdx.x] : 0;
    sh[threadIdx.x] = v;
    __syncthreads();
    for (int ofs = 1; ofs < 512; ofs <<= 1) {
        int t = (threadIdx.x >= ofs) ? sh[threadIdx.x - ofs] : 0;
        __syncthreads();
        sh[threadIdx.x] += t;
        __syncthreads();
    }
    if (threadIdx.x < nbuck) basearr[threadIdx.x] = sh[threadIdx.x] - v;
    if (threadIdx.x == 0) off_all[Ntot_pad] = Etot;
}

// ---- pass 3: per-bucket CSR build + degree-sort permutation ----
__global__ __launch_bounds__(512) void p3_build(const unsigned* __restrict__ pk,
                                                const int* __restrict__ fillarr,
                                                const int* __restrict__ basearr,
                                                int* __restrict__ off_all,
                                                float* __restrict__ dinv,
                                                int* __restrict__ csr,
                                                int* __restrict__ perm) {
    __shared__ int sh[512];
    __shared__ int dhist[64];
    int b    = blockIdx.x;
    int fill = fillarr[b];
    if (fill > BUCKET_CAP) fill = BUCKET_CAP;
    int base = basearr[b];
    const unsigned* reg = pk + (size_t)b * BUCKET_CAP;
    sh[threadIdx.x] = 0;
    if (threadIdx.x < 64) dhist[threadIdx.x] = 0;
    __syncthreads();
    for (int i = threadIdx.x; i < fill; i += 512) atomicAdd(&sh[reg[i] >> 17], 1);
    __syncthreads();
    int cnt = sh[threadIdx.x];
    for (int ofs = 1; ofs < 512; ofs <<= 1) {   // inclusive scan
        int t = (threadIdx.x >= ofs) ? sh[threadIdx.x - ofs] : 0;
        __syncthreads();
        sh[threadIdx.x] += t;
        __syncthreads();
    }
    int excl = sh[threadIdx.x] - cnt;
    int node = b * 512 + threadIdx.x;           // padded-global id
    off_all[node] = base + excl;
    dinv[node]    = rsqrtf((float)(cnt + 1));   // +1 self-loop
    // degree-sort permutation (counting sort by clamped degree)
    int bin = cnt < 63 ? cnt : 63;
    atomicAdd(&dhist[bin], 1);
    __syncthreads();
    if (threadIdx.x == 0) {
        int run = 0;
        for (int i = 0; i < 64; ++i) { int v = dhist[i]; dhist[i] = run; run += v; }
    }
    __syncthreads();
    int pslot = atomicAdd(&dhist[bin], 1);
    perm[b * 512 + pslot] = node;
    __syncthreads();
    sh[threadIdx.x] = excl;   // cursor for CSR scatter
    __syncthreads();
    for (int i = threadIdx.x; i < fill; i += 512) {
        unsigned w    = reg[i];
        int      slot = atomicAdd(&sh[w >> 17], 1);
        csr[base + slot] = (int)(w & 0x1FFFFu);
    }
}

// ---- GEMM body: H[N][M] = fp16((X @ W) * dinv[row]), X fp32 or fp16 ----
template <int K, int M, typename TIN>
__device__ void gemm_body(int bid, const TIN* __restrict__ X, const float* __restrict__ W,
                          const float* __restrict__ dinv, __half* __restrict__ H, int N,
                          char* smem_) {
    constexpr int CG = M / 4, RG = 256 / CG, RB = RG * 4, RBP = RB + 4;  // +4: bank-derotate, keeps 16B align
    float* Xs = (float*)smem_;   // [K][RBP] transposed
    float* Ws = Xs + K * RBP;    // [K][M]
    const int t    = threadIdx.x;
    const int row0 = bid * RB;

    for (int idx = t; idx < K * M; idx += 256) Ws[idx] = W[idx];

    if constexpr (sizeof(TIN) == 4) {
        constexpr int NF4 = RB * K / 4;
        for (int idx = t; idx < NF4; idx += 256) {
            int row = idx / (K / 4), k4 = idx % (K / 4);
            float4 v = make_float4(0.f, 0.f, 0.f, 0.f);
            int gr = row0 + row;
            if (gr < N) v = *(const float4*)((const float*)X + (size_t)gr * K + k4 * 4);
            Xs[(k4 * 4 + 0) * RBP + row] = v.x;
            Xs[(k4 * 4 + 1) * RBP + row] = v.y;
            Xs[(k4 * 4 + 2) * RBP + row] = v.z;
            Xs[(k4 * 4 + 3) * RBP + row] = v.w;
        }
    } else {
        constexpr int NF8 = RB * K / 8;
        for (int idx = t; idx < NF8; idx += 256) {
            int row = idx / (K / 8), k8 = idx % (K / 8);
            int gr = row0 + row;
            union { float4 f4; __half2 h2[4]; } u;
            u.f4 = make_float4(0.f, 0.f, 0.f, 0.f);
            if (gr < N) u.f4 = *(const float4*)((const __half*)X + (size_t)gr * K + k8 * 8);
#pragma unroll
            for (int q = 0; q < 4; ++q) {
                float2 pq = __half22float2(u.h2[q]);
                Xs[(k8 * 8 + 2 * q + 0) * RBP + row] = pq.x;
                Xs[(k8 * 8 + 2 * q + 1) * RBP + row] = pq.y;
            }
        }
    }
    __syncthreads();

    const int cc = t % CG, rr = t / CG;
    float acc[4][4] = {};
#pragma unroll 4
    for (int k = 0; k < K; k++) {
        float4 xv = *(const float4*)(Xs + k * RBP + rr * 4);
        float4 wv = *(const float4*)(Ws + k * M + cc * 4);
        acc[0][0] += xv.x * wv.x; acc[0][1] += xv.x * wv.y; acc[0][2] += xv.x * wv.z; acc[0][3] += xv.x * wv.w;
        acc[1][0] += xv.y * wv.x; acc[1][1] += xv.y * wv.y; acc[1][2] += xv.y * wv.z; acc[1][3] += xv.y * wv.w;
        acc[2][0] += xv.z * wv.x; acc[2][1] += xv.z * wv.y; acc[2][2] += xv.z * wv.z; acc[2][3] += xv.z * wv.w;
        acc[3][0] += xv.w * wv.x; acc[3][1] += xv.w * wv.y; acc[3][2] += xv.w * wv.z; acc[3][3] += xv.w * wv.w;
    }

#pragma unroll
    for (int i = 0; i < 4; i++) {
        int gr = row0 + rr * 4 + i;
        if (gr < N) {
            float sc = dinv[gr];
            __half2* dp = (__half2*)(H + (size_t)gr * M + cc * 4);
            dp[0] = __floats2half2_rn(acc[i][0] * sc, acc[i][1] * sc);
            dp[1] = __floats2half2_rn(acc[i][2] * sc, acc[i][3] * sc);
        }
    }
}

// ---- aggregate: out = relu(dinv*(H[i]+sum H[src]) + b), perm (degree-sorted) order ----
__device__ __forceinline__ float4 load4h(const float2* __restrict__ base, size_t idx) {
    float2 r = base[idx];
    union { float2 f2; __half2 h2[2]; } u;
    u.f2 = r;
    float2 a = __half22float2(u.h2[0]);
    float2 b = __half22float2(u.h2[1]);
    return make_float4(a.x, a.y, b.x, b.y);
}

template <int M>
__device__ void agg_body(int bid, const __half* __restrict__ H,
                         const int* __restrict__ off_g, const int* __restrict__ csr,
                         const float* __restrict__ dinv_g, const float* __restrict__ b,
                         __half* __restrict__ out,
                         const int* __restrict__ permSide, int idBase, int Nloc) {
    constexpr int L   = M / 4;   // lanes per node (4 halves each)
    constexpr int NPW = 64 / L;  // nodes per wave
    int lane = threadIdx.x & 63;
    int wave = threadIdx.x >> 6;
    int fq   = lane & (L - 1);
    int sub  = lane / L;
    int slot = (bid * 4 + wave) * NPW + sub;     // padded slot, always in range
    int g    = permSide[slot];                   // padded-global node id
    int node = g - idBase;                       // side-local
    if (node >= Nloc) return;                    // phantom (deg-0 pad) node
    const float2* H4 = (const float2*)H;
    int j0 = off_g[g], j1 = off_g[g + 1];
    float4 acc = load4h(H4, (size_t)node * L + fq);  // self-loop
    int j = j0;
    for (; j + 8 <= j1; j += 8) {
        int s0 = csr[j],     s1 = csr[j + 1], s2 = csr[j + 2], s3 = csr[j + 3];
        int s4 = csr[j + 4], s5 = csr[j + 5], s6 = csr[j + 6], s7 = csr[j + 7];
        float4 a0 = load4h(H4, (size_t)s0 * L + fq);
        float4 a1 = load4h(H4, (size_t)s1 * L + fq);
        float4 a2 = load4h(H4, (size_t)s2 * L + fq);
        float4 a3 = load4h(H4, (size_t)s3 * L + fq);
        float4 a4 = load4h(H4, (size_t)s4 * L + fq);
        float4 a5 = load4h(H4, (size_t)s5 * L + fq);
        float4 a6 = load4h(H4, (size_t)s6 * L + fq);
        float4 a7 = load4h(H4, (size_t)s7 * L + fq);
        acc.x += (a0.x + a1.x + a2.x + a3.x) + (a4.x + a5.x + a6.x + a7.x);
        acc.y += (a0.y + a1.y + a2.y + a3.y) + (a4.y + a5.y + a6.y + a7.y);
        acc.z += (a0.z + a1.z + a2.z + a3.z) + (a4.z + a5.z + a6.z + a7.z);
        acc.w += (a0.w + a1.w + a2.w + a3.w) + (a4.w + a5.w + a6.w + a7.w);
    }
    for (; j + 4 <= j1; j += 4) {
        int s0 = csr[j], s1 = csr[j + 1], s2 = csr[j + 2], s3 = csr[j + 3];
        float4 a0 = load4h(H4, (size_t)s0 * L + fq);
        float4 a1 = load4h(H4, (size_t)s1 * L + fq);
        float4 a2 = load4h(H4, (size_t)s2 * L + fq);
        float4 a3 = load4h(H4, (size_t)s3 * L + fq);
        acc.x += a0.x + a1.x + a2.x + a3.x;
        acc.y += a0.y + a1.y + a2.y + a3.y;
        acc.z += a0.z + a1.z + a2.z + a3.z;
        acc.w += a0.w + a1.w + a2.w + a3.w;
    }
    for (; j < j1; ++j) {
        float4 a = load4h(H4, (size_t)csr[j] * L + fq);
        acc.x += a.x; acc.y += a.y; acc.z += a.z; acc.w += a.w;
    }
    float  dv = dinv_g[g];
    float4 bb = ((const float4*)b)[fq];
    float  vx = dv * acc.x + bb.x;
    float  vy = dv * acc.y + bb.y;
    float  vz = dv * acc.z + bb.z;
    float  vw = dv * acc.w + bb.w;
    union { float2 f2; __half2 h2[2]; } o;
    o.h2[0] = __floats2half2_rn(vx > 0.f ? vx : 0.f, vy > 0.f ? vy : 0.f);
    o.h2[1] = __floats2half2_rn(vz > 0.f ? vz : 0.f, vw > 0.f ? vw : 0.f);
    ((float2*)out)[(size_t)node * L + fq] = o.f2;
}

// ---- fused two-side kernels ----
__global__ __launch_bounds__(256) void gemmBoth0(const float* __restrict__ Xc, const float* __restrict__ Wc,
                                                 __half* __restrict__ cH, int Nc,
                                                 const float* __restrict__ Xs, const float* __restrict__ Ws,
                                                 __half* __restrict__ sH, int Ns,
                                                 const float* __restrict__ dinv_all, int Nc_pad, int nbC) {
    __shared__ __align__(16) char smem[41984];  // gemm<64,32>: 64*132*4 + 64*32*4
    if (blockIdx.x < nbC) gemm_body<64, 64, float>(blockIdx.x, Xc, Wc, dinv_all, cH, Nc, smem);
    else                  gemm_body<64, 32, float>(blockIdx.x - nbC, Xs, Ws, dinv_all + Nc_pad, sH, Ns, smem);
}

__global__ __launch_bounds__(256) void gemmBoth(const __half* __restrict__ Xc, const float* __restrict__ Wc,
                                                __half* __restrict__ cH, int Nc,
                                                const __half* __restrict__ Xs, const float* __restrict__ Ws,
                                                __half* __restrict__ sH, int Ns,
                                                const float* __restrict__ dinv_all, int Nc_pad, int nbC) {
    __shared__ __align__(16) char smem[34816];  // gemm<64,64>: 64*68*4 + 64*64*4 = 33792
    if (blockIdx.x < nbC) gemm_body<64, 64, __half>(blockIdx.x, Xc, Wc, dinv_all, cH, Nc, smem);
    else                  gemm_body<32, 32, __half>(blockIdx.x - nbC, Xs, Ws, dinv_all + Nc_pad, sH, Ns, smem);
}

__global__ __launch_bounds__(256) void aggBoth(const __half* __restrict__ cH, const __half* __restrict__ sH,
                                               const int* __restrict__ off_all, const int* __restrict__ csr_all,
                                               const float* __restrict__ dinv_all,
                                               const float* __restrict__ bc, const float* __restrict__ bs,
                                               __half* __restrict__ outc, __half* __restrict__ outs,
                                               const int* __restrict__ perm,
                                               int Nc, int Ns, int Nc_pad, int nbC) {
    if (blockIdx.x < nbC)
        agg_body<64>(blockIdx.x, cH, off_all, csr_all, dinv_all, bc, outc, perm, 0, Nc);
    else
        agg_body<32>(blockIdx.x - nbC, sH, off_all, csr_all, dinv_all, bs, outs,
                     perm + Nc_pad, Nc_pad, Ns);
}

// ---- fused pooling + MLP head ----
__device__ __forceinline__ int lbound(const int* __restrict__ a, int n, int key) {
    int lo = 0, hi = n;
    while (lo < hi) {
        int mid = (lo + hi) >> 1;
        if (a[mid] < key) lo = mid + 1; else hi = mid;
    }
    return lo;
}

__global__ __launch_bounds__(128) void poolDense(const __half* __restrict__ cX, const int* __restrict__ c_batch, int Nc,
                                                 const __half* __restrict__ sX, const int* __restrict__ s_batch, int Ns,
                                                 const float* __restrict__ Wd, const float* __restrict__ bd,
                                                 const float* __restrict__ Wo, const float* __restrict__ bo,
                                                 float* __restrict__ outv, float* __restrict__ embed) {
    __shared__ float e[192];
    __shared__ float red[128];
    int g = blockIdx.x, t = threadIdx.x;
    if (t < 64) {
        int lo = lbound(c_batch, Nc, g), hi = lbound(c_batch, Nc, g + 1);
        float mx = 0.f, sm = 0.f;
        for (int i = lo; i < hi; ++i) {
            float v = __half2float(cX[(size_t)i * 64 + t]);
            mx = fmaxf(mx, v); sm += v;
        }
        int cn = hi - lo;
        e[t]      = mx;
        e[64 + t] = sm / (float)(cn > 0 ? cn : 1);
    } else if (t < 96) {
        int f  = t - 64;
        int lo = lbound(s_batch, Ns, g), hi = lbound(s_batch, Ns, g + 1);
        float mx = 0.f, sm = 0.f;
        for (int i = lo; i < hi; ++i) {
            float v = __half2float(sX[(size_t)i * 32 + f]);
            mx = fmaxf(mx, v); sm += v;
        }
        int cn = hi - lo;
        e[128 + f] = mx;
        e[160 + f] = sm / (float)(cn > 0 ? cn : 1);
    }
    __syncthreads();
    for (int k = t; k < 192; k += 128) embed[(size_t)g * 192 + k] = e[k];
    float acc = bd[t];
    for (int k = 0; k < 192; ++k) acc += e[k] * Wd[k * 128 + t];
    float d = acc > 0.f ? acc : 0.f;
    red[t]  = d * Wo[t];
    __syncthreads();
    for (int ofs = 64; ofs > 0; ofs >>= 1) {
        if (t < ofs) red[t] += red[t + ofs];
        __syncthreads();
    }
    if (t == 0) outv[g] = red[0] + bo[0];
}

// ---------------------------------------------------------------------------

extern "C" void kernel_launch(void* const* d_in, const int* in_sizes, int n_in,
                              void* d_out, int out_size, void* d_ws, size_t ws_size,
                              hipStream_t stream) {
    const float* c       = (const float*)d_in[0];
    const int*   c_edge  = (const int*)d_in[1];
    const int*   c_batch = (const int*)d_in[2];
    const float* s       = (const float*)d_in[3];
    const int*   s_edge  = (const int*)d_in[4];
    const int*   s_batch = (const int*)d_in[5];
    const float* Wc0 = (const float*)d_in[6],  *bc0 = (const float*)d_in[7];
    const float* Wc1 = (const float*)d_in[8],  *bc1 = (const float*)d_in[9];
    const float* Wc2 = (const float*)d_in[10], *bc2 = (const float*)d_in[11];
    const float* Ws0 = (const float*)d_in[12], *bs0 = (const float*)d_in[13];
    const float* Ws1 = (const float*)d_in[14], *bs1 = (const float*)d_in[15];
    const float* Ws2 = (const float*)d_in[16], *bs2 = (const float*)d_in[17];
    const float* Wd  = (const float*)d_in[18], *bd  = (const float*)d_in[19];
    const float* Wo  = (const float*)d_in[20], *bo  = (const float*)d_in[21];

    const int Nc = in_sizes[0] / 64;
    const int Ec = in_sizes[1] / 2;
    const int Ns = in_sizes[3] / 64;
    const int Es = in_sizes[4] / 2;
    const int G  = out_size / 193;  // 2048
    const int Nc_pad   = cdiv(Nc, 512) * 512;
    const int Ns_pad   = cdiv(Ns, 512) * 512;
    const int Ntot_pad = Nc_pad + Ns_pad;
    const int Etot     = Ec + Es;
    const int nbuck    = Ntot_pad >> 9;

    // ---- workspace carve ----
    char* p = (char*)d_ws;
    auto  alloc = [&](size_t bytes) -> void* {
        void* r = (void*)p;
        p += (bytes + 255) & ~(size_t)255;
        return r;
    };
    int*      bucket_fill = (int*)alloc(512 * 4);
    int*      bucket_base = (int*)alloc(512 * 4);
    unsigned* pk          = (unsigned*)alloc((size_t)nbuck * BUCKET_CAP * 4);
    int*      off_all     = (int*)alloc(((size_t)Ntot_pad + 1) * 4);
    int*      csr_all     = (int*)alloc((size_t)Etot * 4);
    float*    dinv_all    = (float*)alloc((size_t)Ntot_pad * 4);
    int*      perm        = (int*)alloc((size_t)Ntot_pad * 4);
    __half*   bufC        = (__half*)alloc((size_t)Nc * 64 * 2);
    __half*   bufS        = (__half*)alloc((size_t)Ns * 32 * 2);
    __half*   cH          = (__half*)alloc((size_t)Nc * 64 * 2);
    __half*   sH          = (__half*)alloc((size_t)Ns * 32 * 2);

    float* outv  = (float*)d_out;  // [G]
    float* embed = outv + G;       // [G][192]

    const int nbGmC = cdiv(Nc, 64), nbGm0S = cdiv(Ns, 128), nbGmS = cdiv(Ns, 128);
    const int nbAgC = Nc_pad / 16,  nbAgS  = Ns_pad / 32;

    // 1) CSR build (bucketed, degree-sorted)
    zero_int<<<cdiv(nbuck, 256), 256, 0, stream>>>(bucket_fill, nbuck);
    p1_partition<<<cdiv(Etot, P1_CHUNK), 256, 0, stream>>>(c_edge, Ec, s_edge, Es,
                                                           Nc_pad, Etot, nbuck, bucket_fill, pk);
    p2_scanbuckets<<<1, 512, 0, stream>>>(bucket_fill, nbuck, bucket_base, off_all, Ntot_pad, Etot);
    p3_build<<<nbuck, 512, 0, stream>>>(pk, bucket_fill, bucket_base,
                                        off_all, dinv_all, csr_all, perm);

    // 2) layer 0
    gemmBoth0<<<nbGmC + nbGm0S, 256, 0, stream>>>(c, Wc0, cH, Nc, s, Ws0, sH, Ns,
                                                  dinv_all, Nc_pad, nbGmC);
    aggBoth<<<nbAgC + nbAgS, 256, 0, stream>>>(cH, sH, off_all, csr_all, dinv_all,
                                               bc0, bs0, bufC, bufS, perm, Nc, Ns, Nc_pad, nbAgC);
    // 3) layer 1
    gemmBoth<<<nbGmC + nbGmS, 256, 0, stream>>>(bufC, Wc1, cH, Nc, bufS, Ws1, sH, Ns,
                                                dinv_all, Nc_pad, nbGmC);
    aggBoth<<<nbAgC + nbAgS, 256, 0, stream>>>(cH, sH, off_all, csr_all, dinv_all,
                                               bc1, bs1, bufC, bufS, perm, Nc, Ns, Nc_pad, nbAgC);
    // 4) layer 2
    gemmBoth<<<nbGmC + nbGmS, 256, 0, stream>>>(bufC, Wc2, cH, Nc, bufS, Ws2, sH, Ns,
                                                dinv_all, Nc_pad, nbGmC);
    aggBoth<<<nbAgC + nbAgS, 256, 0, stream>>>(cH, sH, off_all, csr_all, dinv_all,
                                               bc2, bs2, bufC, bufS, perm, Nc, Ns, Nc_pad, nbAgC);

    // 5) fused pooling + MLP
    poolDense<<<G, 128, 0, stream>>>(bufC, c_batch, Nc, bufS, s_batch, Ns,
                                     Wd, bd, Wo, bo, outv, embed);
}

// Round 6
// 418.243 us; speedup vs baseline: 1.0662x; 1.0662x over previous
//
#include <hip/hip_runtime.h>
#include <hip/hip_fp16.h>
#include <math.h>

// ---------------------------------------------------------------------------
// SolventGCN round 6: r4 structure + fp16 activations end-to-end, NO perm
// (degree-sort regressed: locality of consecutive node ids beats divergence).
//   zero -> p1_partition -> p2_scanbuckets -> p3_build -> gemmBoth0
//   -> 3x { aggBoth (natural order, fp16 in/out) / gemmBoth (fp16 in) }
//   -> poolDense.  11 launches.
// Node id space: c ids [0,Nc_pad), s ids [Nc_pad, Nc_pad+Ns_pad) (bucket-padded,
// no bucket mixes sides). Packed edge word = (local_dst<<17)|src (side-local src).
// ---------------------------------------------------------------------------

static inline int cdiv(int a, int b) { return (a + b - 1) / b; }

#define BUCKET_CAP 8192
#define P1_CHUNK   4096

__global__ void zero_int(int* __restrict__ p, int n) {
    int i = blockIdx.x * blockDim.x + threadIdx.x;
    if (i < n) p[i] = 0;
}

// ---- pass 1: partition edges into buckets (packed) ----
__global__ __launch_bounds__(256) void p1_partition(const int* __restrict__ c_edge, int Ec,
                                                    const int* __restrict__ s_edge, int Es,
                                                    int Nc_pad, int Etot, int nbuck,
                                                    int* __restrict__ bucket_fill,
                                                    unsigned* __restrict__ pk) {
    __shared__ unsigned       wbuf[P1_CHUNK];
    __shared__ unsigned short bbuf[P1_CHUNK];
    __shared__ int            hist[512];
    int e0 = blockIdx.x * P1_CHUNK;
    int n  = Etot - e0;
    if (n > P1_CHUNK) n = P1_CHUNK;
    for (int i = threadIdx.x; i < nbuck; i += 256) hist[i] = 0;
    __syncthreads();
    for (int i = threadIdx.x; i < n; i += 256) {
        int e = e0 + i, src, g;
        if (e < Ec) { src = c_edge[e]; g = c_edge[Ec + e]; }
        else        { int e2 = e - Ec; src = s_edge[e2]; g = Nc_pad + s_edge[Es + e2]; }
        int b   = g >> 9;
        wbuf[i] = ((unsigned)(g & 511) << 17) | (unsigned)src;
        bbuf[i] = (unsigned short)b;
        atomicAdd(&hist[b], 1);
    }
    __syncthreads();
    for (int i = threadIdx.x; i < nbuck; i += 256) {
        int h = hist[i];
        hist[i] = h ? atomicAdd(&bucket_fill[i], h) : 0;
    }
    __syncthreads();
    for (int i = threadIdx.x; i < n; i += 256) {
        int b    = bbuf[i];
        int slot = atomicAdd(&hist[b], 1);
        if (slot < BUCKET_CAP) pk[(size_t)b * BUCKET_CAP + slot] = wbuf[i];
    }
}

// ---- pass 2: exclusive scan of bucket fills ----
__global__ __launch_bounds__(512) void p2_scanbuckets(const int* __restrict__ fill, int nbuck,
                                                      int* __restrict__ basearr,
                                                      int* __restrict__ off_all, int Ntot_pad, int Etot) {
    __shared__ int sh[512];
    int v = (threadIdx.x < nbuck) ? fill[threadIdx.x] : 0;
    sh[threadIdx.x] = v;
    __syncthreads();
    for (int ofs = 1; ofs < 512; ofs <<= 1) {
        int t = (threadIdx.x >= ofs) ? sh[threadIdx.x - ofs] : 0;
        __syncthreads();
        sh[threadIdx.x] += t;
        __syncthreads();
    }
    if (threadIdx.x < nbuck) basearr[threadIdx.x] = sh[threadIdx.x] - v;
    if (threadIdx.x == 0) off_all[Ntot_pad] = Etot;
}

// ---- pass 3: per-bucket CSR build (all per-edge atomics in LDS) ----
__global__ __launch_bounds__(512) void p3_build(const unsigned* __restrict__ pk,
                                                const int* __restrict__ fillarr,
                                                const int* __restrict__ basearr,
                                                int* __restrict__ off_all,
                                                float* __restrict__ dinv,
                                                int* __restrict__ csr) {
    __shared__ int sh[512];
    int b    = blockIdx.x;
    int fill = fillarr[b];
    if (fill > BUCKET_CAP) fill = BUCKET_CAP;
    int base = basearr[b];
    const unsigned* reg = pk + (size_t)b * BUCKET_CAP;
    sh[threadIdx.x] = 0;
    __syncthreads();
    for (int i = threadIdx.x; i < fill; i += 512) atomicAdd(&sh[reg[i] >> 17], 1);
    __syncthreads();
    int cnt = sh[threadIdx.x];
    for (int ofs = 1; ofs < 512; ofs <<= 1) {   // inclusive scan
        int t = (threadIdx.x >= ofs) ? sh[threadIdx.x - ofs] : 0;
        __syncthreads();
        sh[threadIdx.x] += t;
        __syncthreads();
    }
    int excl = sh[threadIdx.x] - cnt;
    int node = b * 512 + threadIdx.x;           // padded-global id
    off_all[node] = base + excl;
    dinv[node]    = rsqrtf((float)(cnt + 1));   // +1 self-loop
    __syncthreads();
    sh[threadIdx.x] = excl;   // cursor for CSR scatter
    __syncthreads();
    for (int i = threadIdx.x; i < fill; i += 512) {
        unsigned w    = reg[i];
        int      slot = atomicAdd(&sh[w >> 17], 1);
        csr[base + slot] = (int)(w & 0x1FFFFu);
    }
}

// ---- GEMM body: H[N][M] = fp16((X @ W) * dinv[row]), X fp32 or fp16 ----
template <int K, int M, typename TIN>
__device__ void gemm_body(int bid, const TIN* __restrict__ X, const float* __restrict__ W,
                          const float* __restrict__ dinv, __half* __restrict__ H, int N,
                          char* smem_) {
    constexpr int CG = M / 4, RG = 256 / CG, RB = RG * 4, RBP = RB + 4;
    float* Xs = (float*)smem_;   // [K][RBP] transposed
    float* Ws = Xs + K * RBP;    // [K][M]
    const int t    = threadIdx.x;
    const int row0 = bid * RB;

    for (int idx = t; idx < K * M; idx += 256) Ws[idx] = W[idx];

    if constexpr (sizeof(TIN) == 4) {
        constexpr int NF4 = RB * K / 4;
        for (int idx = t; idx < NF4; idx += 256) {
            int row = idx / (K / 4), k4 = idx % (K / 4);
            float4 v = make_float4(0.f, 0.f, 0.f, 0.f);
            int gr = row0 + row;
            if (gr < N) v = *(const float4*)((const float*)X + (size_t)gr * K + k4 * 4);
            Xs[(k4 * 4 + 0) * RBP + row] = v.x;
            Xs[(k4 * 4 + 1) * RBP + row] = v.y;
            Xs[(k4 * 4 + 2) * RBP + row] = v.z;
            Xs[(k4 * 4 + 3) * RBP + row] = v.w;
        }
    } else {
        constexpr int NF8 = RB * K / 8;
        for (int idx = t; idx < NF8; idx += 256) {
            int row = idx / (K / 8), k8 = idx % (K / 8);
            int gr = row0 + row;
            union { float4 f4; __half2 h2[4]; } u;
            u.f4 = make_float4(0.f, 0.f, 0.f, 0.f);
            if (gr < N) u.f4 = *(const float4*)((const __half*)X + (size_t)gr * K + k8 * 8);
#pragma unroll
            for (int q = 0; q < 4; ++q) {
                float2 pq = __half22float2(u.h2[q]);
                Xs[(k8 * 8 + 2 * q + 0) * RBP + row] = pq.x;
                Xs[(k8 * 8 + 2 * q + 1) * RBP + row] = pq.y;
            }
        }
    }
    __syncthreads();

    const int cc = t % CG, rr = t / CG;
    float acc[4][4] = {};
#pragma unroll 4
    for (int k = 0; k < K; k++) {
        float4 xv = *(const float4*)(Xs + k * RBP + rr * 4);
        float4 wv = *(const float4*)(Ws + k * M + cc * 4);
        acc[0][0] += xv.x * wv.x; acc[0][1] += xv.x * wv.y; acc[0][2] += xv.x * wv.z; acc[0][3] += xv.x * wv.w;
        acc[1][0] += xv.y * wv.x; acc[1][1] += xv.y * wv.y; acc[1][2] += xv.y * wv.z; acc[1][3] += xv.y * wv.w;
        acc[2][0] += xv.z * wv.x; acc[2][1] += xv.z * wv.y; acc[2][2] += xv.z * wv.z; acc[2][3] += xv.z * wv.w;
        acc[3][0] += xv.w * wv.x; acc[3][1] += xv.w * wv.y; acc[3][2] += xv.w * wv.z; acc[3][3] += xv.w * wv.w;
    }

#pragma unroll
    for (int i = 0; i < 4; i++) {
        int gr = row0 + rr * 4 + i;
        if (gr < N) {
            float sc = dinv[gr];
            __half2* dp = (__half2*)(H + (size_t)gr * M + cc * 4);
            dp[0] = __floats2half2_rn(acc[i][0] * sc, acc[i][1] * sc);
            dp[1] = __floats2half2_rn(acc[i][2] * sc, acc[i][3] * sc);
        }
    }
}

// ---- aggregate: out = relu(dinv*(H[i]+sum H[src]) + b), natural node order ----
__device__ __forceinline__ float4 load4h(const float2* __restrict__ base, size_t idx) {
    float2 r = base[idx];
    union { float2 f2; __half2 h2[2]; } u;
    u.f2 = r;
    float2 a = __half22float2(u.h2[0]);
    float2 b = __half22float2(u.h2[1]);
    return make_float4(a.x, a.y, b.x, b.y);
}

template <int M>
__device__ void agg_body(int bid, const __half* __restrict__ H,
                         const int* __restrict__ off_g,   // padded side base
                         const int* __restrict__ csr,
                         const float* __restrict__ dinv_g,
                         const float* __restrict__ b,
                         __half* __restrict__ out, int Nloc) {
    constexpr int L   = M / 4;   // lanes per node (4 halves each)
    constexpr int NPW = 64 / L;  // nodes per wave
    int lane = threadIdx.x & 63;
    int wave = threadIdx.x >> 6;
    int fq   = lane & (L - 1);
    int sub  = lane / L;
    int node = (bid * 4 + wave) * NPW + sub;     // side-local == padded-side id
    if (node >= Nloc) return;
    const float2* H4 = (const float2*)H;
    int j0 = off_g[node], j1 = off_g[node + 1];
    float4 acc = load4h(H4, (size_t)node * L + fq);  // self-loop
    int j = j0;
    for (; j + 8 <= j1; j += 8) {
        int s0 = csr[j],     s1 = csr[j + 1], s2 = csr[j + 2], s3 = csr[j + 3];
        int s4 = csr[j + 4], s5 = csr[j + 5], s6 = csr[j + 6], s7 = csr[j + 7];
        float4 a0 = load4h(H4, (size_t)s0 * L + fq);
        float4 a1 = load4h(H4, (size_t)s1 * L + fq);
        float4 a2 = load4h(H4, (size_t)s2 * L + fq);
        float4 a3 = load4h(H4, (size_t)s3 * L + fq);
        float4 a4 = load4h(H4, (size_t)s4 * L + fq);
        float4 a5 = load4h(H4, (size_t)s5 * L + fq);
        float4 a6 = load4h(H4, (size_t)s6 * L + fq);
        float4 a7 = load4h(H4, (size_t)s7 * L + fq);
        acc.x += (a0.x + a1.x + a2.x + a3.x) + (a4.x + a5.x + a6.x + a7.x);
        acc.y += (a0.y + a1.y + a2.y + a3.y) + (a4.y + a5.y + a6.y + a7.y);
        acc.z += (a0.z + a1.z + a2.z + a3.z) + (a4.z + a5.z + a6.z + a7.z);
        acc.w += (a0.w + a1.w + a2.w + a3.w) + (a4.w + a5.w + a6.w + a7.w);
    }
    for (; j + 4 <= j1; j += 4) {
        int s0 = csr[j], s1 = csr[j + 1], s2 = csr[j + 2], s3 = csr[j + 3];
        float4 a0 = load4h(H4, (size_t)s0 * L + fq);
        float4 a1 = load4h(H4, (size_t)s1 * L + fq);
        float4 a2 = load4h(H4, (size_t)s2 * L + fq);
        float4 a3 = load4h(H4, (size_t)s3 * L + fq);
        acc.x += a0.x + a1.x + a2.x + a3.x;
        acc.y += a0.y + a1.y + a2.y + a3.y;
        acc.z += a0.z + a1.z + a2.z + a3.z;
        acc.w += a0.w + a1.w + a2.w + a3.w;
    }
    for (; j < j1; ++j) {
        float4 a = load4h(H4, (size_t)csr[j] * L + fq);
        acc.x += a.x; acc.y += a.y; acc.z += a.z; acc.w += a.w;
    }
    float  dv = dinv_g[node];
    float4 bb = ((const float4*)b)[fq];
    float  vx = dv * acc.x + bb.x;
    float  vy = dv * acc.y + bb.y;
    float  vz = dv * acc.z + bb.z;
    float  vw = dv * acc.w + bb.w;
    union { float2 f2; __half2 h2[2]; } o;
    o.h2[0] = __floats2half2_rn(vx > 0.f ? vx : 0.f, vy > 0.f ? vy : 0.f);
    o.h2[1] = __floats2half2_rn(vz > 0.f ? vz : 0.f, vw > 0.f ? vw : 0.f);
    ((float2*)out)[(size_t)node * L + fq] = o.f2;
}

// ---- fused two-side kernels ----
__global__ __launch_bounds__(256) void gemmBoth0(const float* __restrict__ Xc, const float* __restrict__ Wc,
                                                 __half* __restrict__ cH, int Nc,
                                                 const float* __restrict__ Xs, const float* __restrict__ Ws,
                                                 __half* __restrict__ sH, int Ns,
                                                 const float* __restrict__ dinv_all, int Nc_pad, int nbC) {
    __shared__ __align__(16) char smem[41984];
    if (blockIdx.x < nbC) gemm_body<64, 64, float>(blockIdx.x, Xc, Wc, dinv_all, cH, Nc, smem);
    else                  gemm_body<64, 32, float>(blockIdx.x - nbC, Xs, Ws, dinv_all + Nc_pad, sH, Ns, smem);
}

__global__ __launch_bounds__(256) void gemmBoth(const __half* __restrict__ Xc, const float* __restrict__ Wc,
                                                __half* __restrict__ cH, int Nc,
                                                const __half* __restrict__ Xs, const float* __restrict__ Ws,
                                                __half* __restrict__ sH, int Ns,
                                                const float* __restrict__ dinv_all, int Nc_pad, int nbC) {
    __shared__ __align__(16) char smem[34816];
    if (blockIdx.x < nbC) gemm_body<64, 64, __half>(blockIdx.x, Xc, Wc, dinv_all, cH, Nc, smem);
    else                  gemm_body<32, 32, __half>(blockIdx.x - nbC, Xs, Ws, dinv_all + Nc_pad, sH, Ns, smem);
}

__global__ __launch_bounds__(256) void aggBoth(const __half* __restrict__ cH, const __half* __restrict__ sH,
                                               const int* __restrict__ off_all, const int* __restrict__ csr_all,
                                               const float* __restrict__ dinv_all,
                                               const float* __restrict__ bc, const float* __restrict__ bs,
                                               __half* __restrict__ outc, __half* __restrict__ outs,
                                               int Nc, int Ns, int Nc_pad, int nbC) {
    if (blockIdx.x < nbC)
        agg_body<64>(blockIdx.x, cH, off_all, csr_all, dinv_all, bc, outc, Nc);
    else
        agg_body<32>(blockIdx.x - nbC, sH, off_all + Nc_pad, csr_all,
                     dinv_all + Nc_pad, bs, outs, Ns);
}

// ---- fused pooling + MLP head ----
__device__ __forceinline__ int lbound(const int* __restrict__ a, int n, int key) {
    int lo = 0, hi = n;
    while (lo < hi) {
        int mid = (lo + hi) >> 1;
        if (a[mid] < key) lo = mid + 1; else hi = mid;
    }
    return lo;
}

__global__ __launch_bounds__(128) void poolDense(const __half* __restrict__ cX, const int* __restrict__ c_batch, int Nc,
                                                 const __half* __restrict__ sX, const int* __restrict__ s_batch, int Ns,
                                                 const float* __restrict__ Wd, const float* __restrict__ bd,
                                                 const float* __restrict__ Wo, const float* __restrict__ bo,
                                                 float* __restrict__ outv, float* __restrict__ embed) {
    __shared__ float e[192];
    __shared__ float red[128];
    int g = blockIdx.x, t = threadIdx.x;
    if (t < 64) {
        int lo = lbound(c_batch, Nc, g), hi = lbound(c_batch, Nc, g + 1);
        float mx = 0.f, sm = 0.f;
        for (int i = lo; i < hi; ++i) {
            float v = __half2float(cX[(size_t)i * 64 + t]);
            mx = fmaxf(mx, v); sm += v;
        }
        int cn = hi - lo;
        e[t]      = mx;
        e[64 + t] = sm / (float)(cn > 0 ? cn : 1);
    } else if (t < 96) {
        int f  = t - 64;
        int lo = lbound(s_batch, Ns, g), hi = lbound(s_batch, Ns, g + 1);
        float mx = 0.f, sm = 0.f;
        for (int i = lo; i < hi; ++i) {
            float v = __half2float(sX[(size_t)i * 32 + f]);
            mx = fmaxf(mx, v); sm += v;
        }
        int cn = hi - lo;
        e[128 + f] = mx;
        e[160 + f] = sm / (float)(cn > 0 ? cn : 1);
    }
    __syncthreads();
    for (int k = t; k < 192; k += 128) embed[(size_t)g * 192 + k] = e[k];
    float acc = bd[t];
    for (int k = 0; k < 192; ++k) acc += e[k] * Wd[k * 128 + t];
    float d = acc > 0.f ? acc : 0.f;
    red[t]  = d * Wo[t];
    __syncthreads();
    for (int ofs = 64; ofs > 0; ofs >>= 1) {
        if (t < ofs) red[t] += red[t + ofs];
        __syncthreads();
    }
    if (t == 0) outv[g] = red[0] + bo[0];
}

// ---------------------------------------------------------------------------

extern "C" void kernel_launch(void* const* d_in, const int* in_sizes, int n_in,
                              void* d_out, int out_size, void* d_ws, size_t ws_size,
                              hipStream_t stream) {
    const float* c       = (const float*)d_in[0];
    const int*   c_edge  = (const int*)d_in[1];
    const int*   c_batch = (const int*)d_in[2];
    const float* s       = (const float*)d_in[3];
    const int*   s_edge  = (const int*)d_in[4];
    const int*   s_batch = (const int*)d_in[5];
    const float* Wc0 = (const float*)d_in[6],  *bc0 = (const float*)d_in[7];
    const float* Wc1 = (const float*)d_in[8],  *bc1 = (const float*)d_in[9];
    const float* Wc2 = (const float*)d_in[10], *bc2 = (const float*)d_in[11];
    const float* Ws0 = (const float*)d_in[12], *bs0 = (const float*)d_in[13];
    const float* Ws1 = (const float*)d_in[14], *bs1 = (const float*)d_in[15];
    const float* Ws2 = (const float*)d_in[16], *bs2 = (const float*)d_in[17];
    const float* Wd  = (const float*)d_in[18], *bd  = (const float*)d_in[19];
    const float* Wo  = (const float*)d_in[20], *bo  = (const float*)d_in[21];

    const int Nc = in_sizes[0] / 64;
    const int Ec = in_sizes[1] / 2;
    const int Ns = in_sizes[3] / 64;
    const int Es = in_sizes[4] / 2;
    const int G  = out_size / 193;  // 2048
    const int Nc_pad   = cdiv(Nc, 512) * 512;
    const int Ns_pad   = cdiv(Ns, 512) * 512;
    const int Ntot_pad = Nc_pad + Ns_pad;
    const int Etot     = Ec + Es;
    const int nbuck    = Ntot_pad >> 9;

    // ---- workspace carve ----
    char* p = (char*)d_ws;
    auto  alloc = [&](size_t bytes) -> void* {
        void* r = (void*)p;
        p += (bytes + 255) & ~(size_t)255;
        return r;
    };
    int*      bucket_fill = (int*)alloc(512 * 4);
    int*      bucket_base = (int*)alloc(512 * 4);
    unsigned* pk          = (unsigned*)alloc((size_t)nbuck * BUCKET_CAP * 4);
    int*      off_all     = (int*)alloc(((size_t)Ntot_pad + 1) * 4);
    int*      csr_all     = (int*)alloc((size_t)Etot * 4);
    float*    dinv_all    = (float*)alloc((size_t)Ntot_pad * 4);
    __half*   bufC        = (__half*)alloc((size_t)Nc * 64 * 2);
    __half*   bufS        = (__half*)alloc((size_t)Ns * 32 * 2);
    __half*   cH          = (__half*)alloc((size_t)Nc * 64 * 2);
    __half*   sH          = (__half*)alloc((size_t)Ns * 32 * 2);

    float* outv  = (float*)d_out;  // [G]
    float* embed = outv + G;       // [G][192]

    const int nbGmC = cdiv(Nc, 64), nbGm0S = cdiv(Ns, 128), nbGmS = cdiv(Ns, 128);
    const int nbAgC = Nc_pad / 16,  nbAgS  = Ns_pad / 32;

    // 1) CSR build (bucketed, LDS atomics only)
    zero_int<<<cdiv(nbuck, 256), 256, 0, stream>>>(bucket_fill, nbuck);
    p1_partition<<<cdiv(Etot, P1_CHUNK), 256, 0, stream>>>(c_edge, Ec, s_edge, Es,
                                                           Nc_pad, Etot, nbuck, bucket_fill, pk);
    p2_scanbuckets<<<1, 512, 0, stream>>>(bucket_fill, nbuck, bucket_base, off_all, Ntot_pad, Etot);
    p3_build<<<nbuck, 512, 0, stream>>>(pk, bucket_fill, bucket_base,
                                        off_all, dinv_all, csr_all);

    // 2) layer 0
    gemmBoth0<<<nbGmC + nbGm0S, 256, 0, stream>>>(c, Wc0, cH, Nc, s, Ws0, sH, Ns,
                                                  dinv_all, Nc_pad, nbGmC);
    aggBoth<<<nbAgC + nbAgS, 256, 0, stream>>>(cH, sH, off_all, csr_all, dinv_all,
                                               bc0, bs0, bufC, bufS, Nc, Ns, Nc_pad, nbAgC);
    // 3) layer 1
    gemmBoth<<<nbGmC + nbGmS, 256, 0, stream>>>(bufC, Wc1, cH, Nc, bufS, Ws1, sH, Ns,
                                                dinv_all, Nc_pad, nbGmC);
    aggBoth<<<nbAgC + nbAgS, 256, 0, stream>>>(cH, sH, off_all, csr_all, dinv_all,
                                               bc1, bs1, bufC, bufS, Nc, Ns, Nc_pad, nbAgC);
    // 4) layer 2
    gemmBoth<<<nbGmC + nbGmS, 256, 0, stream>>>(bufC, Wc2, cH, Nc, bufS, Ws2, sH, Ns,
                                                dinv_all, Nc_pad, nbGmC);
    aggBoth<<<nbAgC + nbAgS, 256, 0, stream>>>(cH, sH, off_all, csr_all, dinv_all,
                                               bc2, bs2, bufC, bufS, Nc, Ns, Nc_pad, nbAgC);

    // 5) fused pooling + MLP
    poolDense<<<G, 128, 0, stream>>>(bufC, c_batch, Nc, bufS, s_batch, Ns,
                                     Wd, bd, Wo, bo, outv, embed);
}

// Round 7
// 367.638 us; speedup vs baseline: 1.2130x; 1.1376x over previous
//
#include <hip/hip_runtime.h>
#include <hip/hip_fp16.h>
#include <math.h>

// ---------------------------------------------------------------------------
// SolventGCN round 7: MFMA (16x16x32 f16) GEMMs, fp32 accumulate.
//   zero -> p1_partition -> p2_scanbuckets -> p3_build -> gemmBoth0(MFMA)
//   -> 3x { aggBoth (fp16 in/out) / gemmBoth(MFMA, fp16 in) } -> poolDense.
// Fragment layouts (gfx950, verified in guide): A[m=lane&15][k=quad*8+j],
// B[k=quad*8+j][n=lane&15], D: col=lane&15, row=quad*4+reg.
// ---------------------------------------------------------------------------

static inline int cdiv(int a, int b) { return (a + b - 1) / b; }

#define BUCKET_CAP 8192
#define P1_CHUNK   4096

typedef _Float16 v8h __attribute__((ext_vector_type(8)));
typedef float    v4f __attribute__((ext_vector_type(4)));

__global__ void zero_int(int* __restrict__ p, int n) {
    int i = blockIdx.x * blockDim.x + threadIdx.x;
    if (i < n) p[i] = 0;
}

// ---- pass 1: partition edges into buckets (packed) ----
__global__ __launch_bounds__(256) void p1_partition(const int* __restrict__ c_edge, int Ec,
                                                    const int* __restrict__ s_edge, int Es,
                                                    int Nc_pad, int Etot, int nbuck,
                                                    int* __restrict__ bucket_fill,
                                                    unsigned* __restrict__ pk) {
    __shared__ unsigned       wbuf[P1_CHUNK];
    __shared__ unsigned short bbuf[P1_CHUNK];
    __shared__ int            hist[512];
    int e0 = blockIdx.x * P1_CHUNK;
    int n  = Etot - e0;
    if (n > P1_CHUNK) n = P1_CHUNK;
    for (int i = threadIdx.x; i < nbuck; i += 256) hist[i] = 0;
    __syncthreads();
    for (int i = threadIdx.x; i < n; i += 256) {
        int e = e0 + i, src, g;
        if (e < Ec) { src = c_edge[e]; g = c_edge[Ec + e]; }
        else        { int e2 = e - Ec; src = s_edge[e2]; g = Nc_pad + s_edge[Es + e2]; }
        int b   = g >> 9;
        wbuf[i] = ((unsigned)(g & 511) << 17) | (unsigned)src;
        bbuf[i] = (unsigned short)b;
        atomicAdd(&hist[b], 1);
    }
    __syncthreads();
    for (int i = threadIdx.x; i < nbuck; i += 256) {
        int h = hist[i];
        hist[i] = h ? atomicAdd(&bucket_fill[i], h) : 0;
    }
    __syncthreads();
    for (int i = threadIdx.x; i < n; i += 256) {
        int b    = bbuf[i];
        int slot = atomicAdd(&hist[b], 1);
        if (slot < BUCKET_CAP) pk[(size_t)b * BUCKET_CAP + slot] = wbuf[i];
    }
}

// ---- pass 2: exclusive scan of bucket fills ----
__global__ __launch_bounds__(512) void p2_scanbuckets(const int* __restrict__ fill, int nbuck,
                                                      int* __restrict__ basearr,
                                                      int* __restrict__ off_all, int Ntot_pad, int Etot) {
    __shared__ int sh[512];
    int v = (threadIdx.x < nbuck) ? fill[threadIdx.x] : 0;
    sh[threadIdx.x] = v;
    __syncthreads();
    for (int ofs = 1; ofs < 512; ofs <<= 1) {
        int t = (threadIdx.x >= ofs) ? sh[threadIdx.x - ofs] : 0;
        __syncthreads();
        sh[threadIdx.x] += t;
        __syncthreads();
    }
    if (threadIdx.x < nbuck) basearr[threadIdx.x] = sh[threadIdx.x] - v;
    if (threadIdx.x == 0) off_all[Ntot_pad] = Etot;
}

// ---- pass 3: per-bucket CSR build (all per-edge atomics in LDS) ----
__global__ __launch_bounds__(512) void p3_build(const unsigned* __restrict__ pk,
                                                const int* __restrict__ fillarr,
                                                const int* __restrict__ basearr,
                                                int* __restrict__ off_all,
                                                float* __restrict__ dinv,
                                                int* __restrict__ csr) {
    __shared__ int sh[512];
    int b    = blockIdx.x;
    int fill = fillarr[b];
    if (fill > BUCKET_CAP) fill = BUCKET_CAP;
    int base = basearr[b];
    const unsigned* reg = pk + (size_t)b * BUCKET_CAP;
    sh[threadIdx.x] = 0;
    __syncthreads();
    for (int i = threadIdx.x; i < fill; i += 512) atomicAdd(&sh[reg[i] >> 17], 1);
    __syncthreads();
    int cnt = sh[threadIdx.x];
    for (int ofs = 1; ofs < 512; ofs <<= 1) {   // inclusive scan
        int t = (threadIdx.x >= ofs) ? sh[threadIdx.x - ofs] : 0;
        __syncthreads();
        sh[threadIdx.x] += t;
        __syncthreads();
    }
    int excl = sh[threadIdx.x] - cnt;
    int node = b * 512 + threadIdx.x;           // padded-global id
    off_all[node] = base + excl;
    dinv[node]    = rsqrtf((float)(cnt + 1));   // +1 self-loop
    __syncthreads();
    sh[threadIdx.x] = excl;   // cursor for CSR scatter
    __syncthreads();
    for (int i = threadIdx.x; i < fill; i += 512) {
        unsigned w    = reg[i];
        int      slot = atomicAdd(&sh[w >> 17], 1);
        csr[base + slot] = (int)(w & 0x1FFFFu);
    }
}

// ---- MFMA GEMM body: H[N][M] = fp16((X @ W) * dinv[row]) ----
// Block = 4 waves, 64 rows. X staged fp16 in LDS [64][K+8]; W pre-swizzled
// into B-fragment order (16B/lane contiguous). fp32 accumulation via MFMA.
template <int K, int M, typename TIN>
__device__ void gemm_mfma(int bid, const TIN* __restrict__ X, const float* __restrict__ W,
                          const float* __restrict__ dinv, __half* __restrict__ H, int N,
                          char* smem_) {
    constexpr int RB = 64;        // rows per block
    constexpr int KP = K + 8;     // padded LDS row (halves)
    constexpr int NT = M / 16;    // 16-col tiles
    constexpr int KS = K / 32;    // 32-k steps
    _Float16* Xh = (_Float16*)smem_;           // [RB][KP]
    _Float16* Wz = Xh + RB * KP;               // [NT*KS*64][8]
    const int t    = threadIdx.x;
    const int row0 = bid * RB;

    // stage W fragments: entry (ntl,ks,lane) = W[ks*32+quad*8+j][ntl*16+(lane&15)]
    constexpr int WENT = NT * KS * 64;
    for (int idx = t; idx < WENT; idx += 256) {
        int lane = idx & 63, rest = idx >> 6;
        int ks = rest % KS, ntl = rest / KS;
        int kbase = ks * 32 + (lane >> 4) * 8;
        int col   = ntl * 16 + (lane & 15);
        union { float4 f4; _Float16 h[8]; } u;
#pragma unroll
        for (int j = 0; j < 8; ++j) u.h[j] = (_Float16)W[(kbase + j) * M + col];
        *(float4*)(Wz + idx * 8) = u.f4;
    }
    // stage X (fp32 -> convert, fp16 -> raw 16B copy)
    if constexpr (sizeof(TIN) == 4) {
        constexpr int NI = RB * K / 4;
        for (int idx = t; idx < NI; idx += 256) {
            int row = idx / (K / 4), k4 = idx % (K / 4);
            int gr = row0 + row;
            float4 v = make_float4(0.f, 0.f, 0.f, 0.f);
            if (gr < N) v = *(const float4*)((const float*)X + (size_t)gr * K + k4 * 4);
            union { float2 f2; _Float16 h[4]; } u;
            u.h[0] = (_Float16)v.x; u.h[1] = (_Float16)v.y;
            u.h[2] = (_Float16)v.z; u.h[3] = (_Float16)v.w;
            *(float2*)(Xh + row * KP + k4 * 4) = u.f2;
        }
    } else {
        constexpr int NI = RB * K / 8;
        for (int idx = t; idx < NI; idx += 256) {
            int row = idx / (K / 8), k8 = idx % (K / 8);
            int gr = row0 + row;
            float4 v = make_float4(0.f, 0.f, 0.f, 0.f);
            if (gr < N) v = *(const float4*)((const __half*)X + (size_t)gr * K + k8 * 8);
            *(float4*)(Xh + row * KP + k8 * 8) = v;
        }
    }
    __syncthreads();

    const int wave = t >> 6, lane = t & 63;
    const int quad = lane >> 4, nl = lane & 15;
    const int rowA = wave * 16 + nl;   // A-operand row for this lane

    v4f acc[NT];
#pragma unroll
    for (int i = 0; i < NT; ++i) acc[i] = (v4f){0.f, 0.f, 0.f, 0.f};

#pragma unroll
    for (int ks = 0; ks < KS; ++ks) {
        v8h a = *(const v8h*)(Xh + rowA * KP + ks * 32 + quad * 8);
#pragma unroll
        for (int ntl = 0; ntl < NT; ++ntl) {
            v8h b = *(const v8h*)(Wz + ((ntl * KS + ks) * 64 + lane) * 8);
            acc[ntl] = __builtin_amdgcn_mfma_f32_16x16x32_f16(a, b, acc[ntl], 0, 0, 0);
        }
    }

    // epilogue: D col=nl, row=quad*4+r
#pragma unroll
    for (int r = 0; r < 4; ++r) {
        int gr = row0 + wave * 16 + quad * 4 + r;
        if (gr < N) {
            float dv = dinv[gr];
#pragma unroll
            for (int ntl = 0; ntl < NT; ++ntl)
                H[(size_t)gr * M + ntl * 16 + nl] = __float2half(acc[ntl][r] * dv);
        }
    }
}

// ---- aggregate: out = relu(dinv*(H[i]+sum H[src]) + b), natural node order ----
__device__ __forceinline__ float4 load4h(const float2* __restrict__ base, size_t idx) {
    float2 r = base[idx];
    union { float2 f2; __half2 h2[2]; } u;
    u.f2 = r;
    float2 a = __half22float2(u.h2[0]);
    float2 b = __half22float2(u.h2[1]);
    return make_float4(a.x, a.y, b.x, b.y);
}

template <int M>
__device__ void agg_body(int bid, const __half* __restrict__ H,
                         const int* __restrict__ off_g,
                         const int* __restrict__ csr,
                         const float* __restrict__ dinv_g,
                         const float* __restrict__ b,
                         __half* __restrict__ out, int Nloc) {
    constexpr int L   = M / 4;   // lanes per node (4 halves each)
    constexpr int NPW = 64 / L;  // nodes per wave
    int lane = threadIdx.x & 63;
    int wave = threadIdx.x >> 6;
    int fq   = lane & (L - 1);
    int sub  = lane / L;
    int node = (bid * 4 + wave) * NPW + sub;
    if (node >= Nloc) return;
    const float2* H4 = (const float2*)H;
    int j0 = off_g[node], j1 = off_g[node + 1];
    float4 acc = load4h(H4, (size_t)node * L + fq);  // self-loop
    int j = j0;
    for (; j + 8 <= j1; j += 8) {
        int s0 = csr[j],     s1 = csr[j + 1], s2 = csr[j + 2], s3 = csr[j + 3];
        int s4 = csr[j + 4], s5 = csr[j + 5], s6 = csr[j + 6], s7 = csr[j + 7];
        float4 a0 = load4h(H4, (size_t)s0 * L + fq);
        float4 a1 = load4h(H4, (size_t)s1 * L + fq);
        float4 a2 = load4h(H4, (size_t)s2 * L + fq);
        float4 a3 = load4h(H4, (size_t)s3 * L + fq);
        float4 a4 = load4h(H4, (size_t)s4 * L + fq);
        float4 a5 = load4h(H4, (size_t)s5 * L + fq);
        float4 a6 = load4h(H4, (size_t)s6 * L + fq);
        float4 a7 = load4h(H4, (size_t)s7 * L + fq);
        acc.x += (a0.x + a1.x + a2.x + a3.x) + (a4.x + a5.x + a6.x + a7.x);
        acc.y += (a0.y + a1.y + a2.y + a3.y) + (a4.y + a5.y + a6.y + a7.y);
        acc.z += (a0.z + a1.z + a2.z + a3.z) + (a4.z + a5.z + a6.z + a7.z);
        acc.w += (a0.w + a1.w + a2.w + a3.w) + (a4.w + a5.w + a6.w + a7.w);
    }
    for (; j + 4 <= j1; j += 4) {
        int s0 = csr[j], s1 = csr[j + 1], s2 = csr[j + 2], s3 = csr[j + 3];
        float4 a0 = load4h(H4, (size_t)s0 * L + fq);
        float4 a1 = load4h(H4, (size_t)s1 * L + fq);
        float4 a2 = load4h(H4, (size_t)s2 * L + fq);
        float4 a3 = load4h(H4, (size_t)s3 * L + fq);
        acc.x += a0.x + a1.x + a2.x + a3.x;
        acc.y += a0.y + a1.y + a2.y + a3.y;
        acc.z += a0.z + a1.z + a2.z + a3.z;
        acc.w += a0.w + a1.w + a2.w + a3.w;
    }
    for (; j < j1; ++j) {
        float4 a = load4h(H4, (size_t)csr[j] * L + fq);
        acc.x += a.x; acc.y += a.y; acc.z += a.z; acc.w += a.w;
    }
    float  dv = dinv_g[node];
    float4 bb = ((const float4*)b)[fq];
    float  vx = dv * acc.x + bb.x;
    float  vy = dv * acc.y + bb.y;
    float  vz = dv * acc.z + bb.z;
    float  vw = dv * acc.w + bb.w;
    union { float2 f2; __half2 h2[2]; } o;
    o.h2[0] = __floats2half2_rn(vx > 0.f ? vx : 0.f, vy > 0.f ? vy : 0.f);
    o.h2[1] = __floats2half2_rn(vz > 0.f ? vz : 0.f, vw > 0.f ? vw : 0.f);
    ((float2*)out)[(size_t)node * L + fq] = o.f2;
}

// ---- fused two-side kernels ----
__global__ __launch_bounds__(256) void gemmBoth0(const float* __restrict__ Xc, const float* __restrict__ Wc,
                                                 __half* __restrict__ cH, int Nc,
                                                 const float* __restrict__ Xs, const float* __restrict__ Ws,
                                                 __half* __restrict__ sH, int Ns,
                                                 const float* __restrict__ dinv_all, int Nc_pad, int nbC) {
    __shared__ __align__(16) char smem[17408];
    if (blockIdx.x < nbC) gemm_mfma<64, 64, float>(blockIdx.x, Xc, Wc, dinv_all, cH, Nc, smem);
    else                  gemm_mfma<64, 32, float>(blockIdx.x - nbC, Xs, Ws, dinv_all + Nc_pad, sH, Ns, smem);
}

__global__ __launch_bounds__(256) void gemmBoth(const __half* __restrict__ Xc, const float* __restrict__ Wc,
                                                __half* __restrict__ cH, int Nc,
                                                const __half* __restrict__ Xs, const float* __restrict__ Ws,
                                                __half* __restrict__ sH, int Ns,
                                                const float* __restrict__ dinv_all, int Nc_pad, int nbC) {
    __shared__ __align__(16) char smem[17408];
    if (blockIdx.x < nbC) gemm_mfma<64, 64, __half>(blockIdx.x, Xc, Wc, dinv_all, cH, Nc, smem);
    else                  gemm_mfma<32, 32, __half>(blockIdx.x - nbC, Xs, Ws, dinv_all + Nc_pad, sH, Ns, smem);
}

__global__ __launch_bounds__(256) void aggBoth(const __half* __restrict__ cH, const __half* __restrict__ sH,
                                               const int* __restrict__ off_all, const int* __restrict__ csr_all,
                                               const float* __restrict__ dinv_all,
                                               const float* __restrict__ bc, const float* __restrict__ bs,
                                               __half* __restrict__ outc, __half* __restrict__ outs,
                                               int Nc, int Ns, int Nc_pad, int nbC) {
    if (blockIdx.x < nbC)
        agg_body<64>(blockIdx.x, cH, off_all, csr_all, dinv_all, bc, outc, Nc);
    else
        agg_body<32>(blockIdx.x - nbC, sH, off_all + Nc_pad, csr_all,
                     dinv_all + Nc_pad, bs, outs, Ns);
}

// ---- fused pooling + MLP head ----
__device__ __forceinline__ int lbound(const int* __restrict__ a, int n, int key) {
    int lo = 0, hi = n;
    while (lo < hi) {
        int mid = (lo + hi) >> 1;
        if (a[mid] < key) lo = mid + 1; else hi = mid;
    }
    return lo;
}

__global__ __launch_bounds__(128) void poolDense(const __half* __restrict__ cX, const int* __restrict__ c_batch, int Nc,
                                                 const __half* __restrict__ sX, const int* __restrict__ s_batch, int Ns,
                                                 const float* __restrict__ Wd, const float* __restrict__ bd,
                                                 const float* __restrict__ Wo, const float* __restrict__ bo,
                                                 float* __restrict__ outv, float* __restrict__ embed) {
    __shared__ float e[192];
    __shared__ float red[128];
    int g = blockIdx.x, t = threadIdx.x;
    if (t < 64) {
        int lo = lbound(c_batch, Nc, g), hi = lbound(c_batch, Nc, g + 1);
        float mx = 0.f, sm = 0.f;
        for (int i = lo; i < hi; ++i) {
            float v = __half2float(cX[(size_t)i * 64 + t]);
            mx = fmaxf(mx, v); sm += v;
        }
        int cn = hi - lo;
        e[t]      = mx;
        e[64 + t] = sm / (float)(cn > 0 ? cn : 1);
    } else if (t < 96) {
        int f  = t - 64;
        int lo = lbound(s_batch, Ns, g), hi = lbound(s_batch, Ns, g + 1);
        float mx = 0.f, sm = 0.f;
        for (int i = lo; i < hi; ++i) {
            float v = __half2float(sX[(size_t)i * 32 + f]);
            mx = fmaxf(mx, v); sm += v;
        }
        int cn = hi - lo;
        e[128 + f] = mx;
        e[160 + f] = sm / (float)(cn > 0 ? cn : 1);
    }
    __syncthreads();
    for (int k = t; k < 192; k += 128) embed[(size_t)g * 192 + k] = e[k];
    float acc = bd[t];
    for (int k = 0; k < 192; ++k) acc += e[k] * Wd[k * 128 + t];
    float d = acc > 0.f ? acc : 0.f;
    red[t]  = d * Wo[t];
    __syncthreads();
    for (int ofs = 64; ofs > 0; ofs >>= 1) {
        if (t < ofs) red[t] += red[t + ofs];
        __syncthreads();
    }
    if (t == 0) outv[g] = red[0] + bo[0];
}

// ---------------------------------------------------------------------------

extern "C" void kernel_launch(void* const* d_in, const int* in_sizes, int n_in,
                              void* d_out, int out_size, void* d_ws, size_t ws_size,
                              hipStream_t stream) {
    const float* c       = (const float*)d_in[0];
    const int*   c_edge  = (const int*)d_in[1];
    const int*   c_batch = (const int*)d_in[2];
    const float* s       = (const float*)d_in[3];
    const int*   s_edge  = (const int*)d_in[4];
    const int*   s_batch = (const int*)d_in[5];
    const float* Wc0 = (const float*)d_in[6],  *bc0 = (const float*)d_in[7];
    const float* Wc1 = (const float*)d_in[8],  *bc1 = (const float*)d_in[9];
    const float* Wc2 = (const float*)d_in[10], *bc2 = (const float*)d_in[11];
    const float* Ws0 = (const float*)d_in[12], *bs0 = (const float*)d_in[13];
    const float* Ws1 = (const float*)d_in[14], *bs1 = (const float*)d_in[15];
    const float* Ws2 = (const float*)d_in[16], *bs2 = (const float*)d_in[17];
    const float* Wd  = (const float*)d_in[18], *bd  = (const float*)d_in[19];
    const float* Wo  = (const float*)d_in[20], *bo  = (const float*)d_in[21];

    const int Nc = in_sizes[0] / 64;
    const int Ec = in_sizes[1] / 2;
    const int Ns = in_sizes[3] / 64;
    const int Es = in_sizes[4] / 2;
    const int G  = out_size / 193;  // 2048
    const int Nc_pad   = cdiv(Nc, 512) * 512;
    const int Ns_pad   = cdiv(Ns, 512) * 512;
    const int Ntot_pad = Nc_pad + Ns_pad;
    const int Etot     = Ec + Es;
    const int nbuck    = Ntot_pad >> 9;

    // ---- workspace carve ----
    char* p = (char*)d_ws;
    auto  alloc = [&](size_t bytes) -> void* {
        void* r = (void*)p;
        p += (bytes + 255) & ~(size_t)255;
        return r;
    };
    int*      bucket_fill = (int*)alloc(512 * 4);
    int*      bucket_base = (int*)alloc(512 * 4);
    unsigned* pk          = (unsigned*)alloc((size_t)nbuck * BUCKET_CAP * 4);
    int*      off_all     = (int*)alloc(((size_t)Ntot_pad + 1) * 4);
    int*      csr_all     = (int*)alloc((size_t)Etot * 4);
    float*    dinv_all    = (float*)alloc((size_t)Ntot_pad * 4);
    __half*   bufC        = (__half*)alloc((size_t)Nc * 64 * 2);
    __half*   bufS        = (__half*)alloc((size_t)Ns * 32 * 2);
    __half*   cH          = (__half*)alloc((size_t)Nc * 64 * 2);
    __half*   sH          = (__half*)alloc((size_t)Ns * 32 * 2);

    float* outv  = (float*)d_out;  // [G]
    float* embed = outv + G;       // [G][192]

    const int nbGmC = cdiv(Nc, 64), nbGmS = cdiv(Ns, 64);
    const int nbAgC = Nc_pad / 16,  nbAgS = Ns_pad / 32;

    // 1) CSR build (bucketed, LDS atomics only)
    zero_int<<<cdiv(nbuck, 256), 256, 0, stream>>>(bucket_fill, nbuck);
    p1_partition<<<cdiv(Etot, P1_CHUNK), 256, 0, stream>>>(c_edge, Ec, s_edge, Es,
                                                           Nc_pad, Etot, nbuck, bucket_fill, pk);
    p2_scanbuckets<<<1, 512, 0, stream>>>(bucket_fill, nbuck, bucket_base, off_all, Ntot_pad, Etot);
    p3_build<<<nbuck, 512, 0, stream>>>(pk, bucket_fill, bucket_base,
                                        off_all, dinv_all, csr_all);

    // 2) layer 0
    gemmBoth0<<<nbGmC + nbGmS, 256, 0, stream>>>(c, Wc0, cH, Nc, s, Ws0, sH, Ns,
                                                 dinv_all, Nc_pad, nbGmC);
    aggBoth<<<nbAgC + nbAgS, 256, 0, stream>>>(cH, sH, off_all, csr_all, dinv_all,
                                               bc0, bs0, bufC, bufS, Nc, Ns, Nc_pad, nbAgC);
    // 3) layer 1
    gemmBoth<<<nbGmC + nbGmS, 256, 0, stream>>>(bufC, Wc1, cH, Nc, bufS, Ws1, sH, Ns,
                                                dinv_all, Nc_pad, nbGmC);
    aggBoth<<<nbAgC + nbAgS, 256, 0, stream>>>(cH, sH, off_all, csr_all, dinv_all,
                                               bc1, bs1, bufC, bufS, Nc, Ns, Nc_pad, nbAgC);
    // 4) layer 2
    gemmBoth<<<nbGmC + nbGmS, 256, 0, stream>>>(bufC, Wc2, cH, Nc, bufS, Ws2, sH, Ns,
                                                dinv_all, Nc_pad, nbGmC);
    aggBoth<<<nbAgC + nbAgS, 256, 0, stream>>>(cH, sH, off_all, csr_all, dinv_all,
                                               bc2, bs2, bufC, bufS, Nc, Ns, Nc_pad, nbAgC);

    // 5) fused pooling + MLP
    poolDense<<<G, 128, 0, stream>>>(bufC, c_batch, Nc, bufS, s_batch, Ns,
                                     Wd, bd, Wo, bo, outv, embed);
}